// Round 5
// baseline (1089.854 us; speedup 1.0000x reference)
//
#include <hip/hip_runtime.h>

// SlayerLoihiMLP: replicate the harness's *float32* numpy reference bit-exactly.
// GEMMs: sequential ascending-index f32 accumulation (mul then add, no FMA —
//   x/s1 are exactly {0,1} so only ORDER matters).
// psp conv: f32, taps = kerint/64 (exact), summed oldest-tap-first (ascending k
//   over the reversed kernel, like `for k: y += w[k]*xpad[..,k:k+T]`).
// Neuron dynamics: bit-exact int32 (jnp wrap semantics).
// No FP contraction anywhere on the matched path (#pragma clang fp contract).

constexpr int kT     = 512;
constexpr int kCIN   = 512;
constexpr int kHID   = 1024;
constexpr int kCOUT  = 256;
constexpr int kB     = 32;
constexpr int kKMAX  = 96;     // actual SRM kernel length = 88 (hand-simulated)
constexpr int kTHETA = 5120;   // 80 << 6
constexpr int kTB    = kT / 8; // packed bytes per (b,o) row = 64

__device__ __forceinline__ int decay_i(int x, int mult) {
    unsigned ax = (x >= 0) ? (unsigned)x : (0u - (unsigned)x);
    unsigned p  = ax * (unsigned)mult;   // int32 wrap like jnp
    int sh = ((int)p) >> 12;             // arithmetic shift like jnp int32 >>
    return (x >= 0) ? sh : (int)(0u - (unsigned)sh);
}

// taps: kerint[tau] = 64 * SRM_KERNEL[tau] (exact small ints); kerf = kerint/64
__device__ __forceinline__ int build_ker_f(float* kerf) {
    int u = 64, v = 64;
    kerf[0] = 1.0f;  // 64/64
    int i = 1;
    while (v > 0 && i < kKMAX) {
        u = (u * 3072) >> 12;
        v = ((v * 3968) >> 12) + u;
        kerf[i++] = (float)v * 0.015625f;  // /64, exact (v <= 194)
    }
    return i;  // 88, includes trailing zero tap
}

// ---------------- Layer 1: f32 GEMM + SRM conv + int32 scan, fused ------------
constexpr int kOT1 = 8;

__global__ __launch_bounds__(512) void k1_fused(const float* __restrict__ X,
                                                const float* __restrict__ W,
                                                unsigned char* __restrict__ SP) {
#pragma clang fp contract(off)
    __shared__ float         wlds[kOT1 * kCIN];  // 16 KB
    __shared__ float         hbuf[kT];           // 2 KB
    __shared__ int           cur[kOT1][kT];      // 16 KB
    __shared__ unsigned char sbuf[kOT1][kT];     // 4 KB
    __shared__ float         ker[kKMAX];         // ~38.5 KB total
    __shared__ int           kn_s;

    const int t     = threadIdx.x;               // one thread per timestep
    const int b     = blockIdx.x >> 7;           // 128 blocks per batch
    const int obase = (blockIdx.x & 127) * kOT1;

    if (t == 0) kn_s = build_ker_f(ker);
    for (int idx = t; idx < kOT1 * kCIN; idx += 512)
        wlds[idx] = W[(size_t)obase * kCIN + idx];
    __syncthreads();

    // GEMM: acc[j] = sum_i W[o,i]*X[b,i,t], i ascending, f32 mul+add (no FMA).
    const float* xb = X + ((size_t)b * kCIN) * kT + t;
    float acc[kOT1];
#pragma unroll
    for (int j = 0; j < kOT1; ++j) acc[j] = 0.0f;
    for (int i = 0; i < kCIN; ++i) {
        const float xv = xb[(size_t)i * kT];     // coalesced over t-lanes
#pragma unroll
        for (int j = 0; j < kOT1; ++j) {
            const float p = wlds[j * kCIN + i] * xv;
            acc[j] = acc[j] + p;
        }
    }

    // causal conv: y[t] = sum over taps, OLDEST FIRST (ascending k of the
    // reversed kernel == tau descending). Skipped pad-taps contribute exact +0.
    const int kn = kn_s;
    for (int j = 0; j < kOT1; ++j) {
        __syncthreads();
        hbuf[t] = acc[j];
        __syncthreads();
        float c = 0.0f;
        const int kmax = min(t + 1, kn);
        for (int tau = kmax - 1; tau >= 0; --tau) {
            const float p = ker[tau] * hbuf[t - tau];
            c = c + p;
        }
        cur[j][t] = (int)(c * 64.0f);  // *64 exact (pow2), trunc toward 0
    }
    __syncthreads();

    // serial int32 Loihi dynamics; write PRE-DELAYED spikes
    if (t < kOT1) {
        int u = 0, v = 0;
        sbuf[t][0] = 0;  // delay_shift
        for (int s = 0; s < kT; ++s) {
            int un = (int)((unsigned)decay_i(u, 3072) + (unsigned)cur[t][s]);
            int vn = (int)((unsigned)decay_i(v, 3968) + (unsigned)un);
            int sp = (vn >= kTHETA) ? 1 : 0;
            if (sp) vn = 0;
            u = un; v = vn;
            if (s + 1 < kT) sbuf[t][s + 1] = (unsigned char)sp;
        }
    }
    __syncthreads();

    // bit-pack delayed spikes: SP[(b*HID+o)*64 + (t>>3)], bit (t&7)
    for (int idx = t; idx < kOT1 * kTB; idx += 512) {
        const int j = idx >> 6, byi = idx & 63;
        unsigned byte = 0;
#pragma unroll
        for (int k = 0; k < 8; ++k)
            byte |= (unsigned)sbuf[j][byi * 8 + k] << k;
        SP[((size_t)(b * kHID + obase + j)) * kTB + byi] = (unsigned char)byte;
    }
}

// ---------------- Layer 2: f32 GEMM over packed spikes + conv + scan + out ----
constexpr int kOT2 = 8;

__global__ __launch_bounds__(512) void k2_fused(const unsigned char* __restrict__ SP,
                                                const float* __restrict__ W,
                                                float* __restrict__ O) {
#pragma clang fp contract(off)
    __shared__ float         wlds[kOT2 * kHID];  // 32 KB
    __shared__ float         hbuf[kT];           // 2 KB
    __shared__ int           cur[kOT2][kT];      // 16 KB
    __shared__ unsigned char sbuf[kOT2][kT];     // 4 KB
    __shared__ float         ker[kKMAX];         // ~54.5 KB total
    __shared__ int           kn_s;

    const int t     = threadIdx.x;
    const int b     = blockIdx.x >> 5;           // 32 blocks per batch
    const int obase = (blockIdx.x & 31) * kOT2;

    if (t == 0) kn_s = build_ker_f(ker);
    for (int idx = t; idx < kOT2 * kHID; idx += 512)
        wlds[idx] = W[(size_t)obase * kHID + idx];
    __syncthreads();

    // GEMM over {0,1} spikes: ordered f32 adds of selected W2 entries,
    // h ascending (mul by 0/1 then add == select-and-add, bit-identical).
    const unsigned char* sb = SP + ((size_t)b * kHID) * kTB + (t >> 3);
    const int bitsh = t & 7;
    float acc[kOT2];
#pragma unroll
    for (int j = 0; j < kOT2; ++j) acc[j] = 0.0f;
    for (int i = 0; i < kHID; ++i) {
        const float sv = (float)((sb[(size_t)i * kTB] >> bitsh) & 1);
#pragma unroll
        for (int j = 0; j < kOT2; ++j) {
            const float p = wlds[j * kHID + i] * sv;
            acc[j] = acc[j] + p;
        }
    }

    const int kn = kn_s;
    for (int j = 0; j < kOT2; ++j) {
        __syncthreads();
        hbuf[t] = acc[j];
        __syncthreads();
        float c = 0.0f;
        const int kmax = min(t + 1, kn);
        for (int tau = kmax - 1; tau >= 0; --tau) {
            const float p = ker[tau] * hbuf[t - tau];
            c = c + p;
        }
        cur[j][t] = (int)(c * 64.0f);
    }
    __syncthreads();

    if (t < kOT2) {
        int u = 0, v = 0;
        sbuf[t][0] = 0;  // delay_shift on final output
        for (int s = 0; s < kT; ++s) {
            int un = (int)((unsigned)decay_i(u, 3072) + (unsigned)cur[t][s]);
            int vn = (int)((unsigned)decay_i(v, 3968) + (unsigned)un);
            int sp = (vn >= kTHETA) ? 1 : 0;
            if (sp) vn = 0;
            u = un; v = vn;
            if (s + 1 < kT) sbuf[t][s + 1] = (unsigned char)sp;
        }
    }
    __syncthreads();

    for (int idx = t; idx < kOT2 * kT; idx += 512) {
        const int j = idx >> 9, tt = idx & 511;
        O[((size_t)(b * kCOUT + obase + j)) * kT + tt] = (float)sbuf[j][tt];
    }
}

extern "C" void kernel_launch(void* const* d_in, const int* in_sizes, int n_in,
                              void* d_out, int out_size, void* d_ws, size_t ws_size,
                              hipStream_t stream) {
    const float* X  = (const float*)d_in[0];   // (32,512,1,1,512) spikes {0,1}
    const float* W1 = (const float*)d_in[1];   // (1024,512)
    const float* W2 = (const float*)d_in[2];   // (256,1024)
    float* OUT = (float*)d_out;                // (32,256,1,1,512)

    unsigned char* s1p = (unsigned char*)d_ws; // 2 MiB bit-packed delayed spikes

    hipLaunchKernelGGL(k1_fused, dim3(kB * (kHID / kOT1)), dim3(512), 0, stream,
                       X, W1, s1p);
    hipLaunchKernelGGL(k2_fused, dim3(kB * (kCOUT / kOT2)), dim3(512), 0, stream,
                       s1p, W2, OUT);
}

// Round 6
// 680.648 us; speedup vs baseline: 1.6012x; 1.6012x over previous
//
#include <hip/hip_runtime.h>

// SlayerLoihiMLP: bit-exact f32 replication of the numpy reference (verified
// round 5, absmax 0.0), now sparse. Exactness invariants preserved:
//  - GEMM: per-output ordered ascending-i f32 sum; skipping x==0 terms is
//    bit-exact (+0.0 adds; RNE running sums never produce -0.0), and w*1.0f
//    is exact, so sparse terms are plain ordered adds.
//  - conv: f32 mul+add (NO fma/contract), taps oldest-first (tau descending),
//    taps = (64*SRM_KERNEL)/64 exact; *64.0f then trunc-to-int32.
//  - neuron dynamics: bit-exact int32 with jnp wrap semantics.

constexpr int kT     = 512;
constexpr int kCIN   = 512;
constexpr int kHID   = 1024;
constexpr int kCOUT  = 256;
constexpr int kB     = 32;
constexpr int kKMAX  = 96;     // actual SRM kernel length = 88
constexpr int kTHETA = 5120;   // 80 << 6
constexpr int kOT    = 8;      // output channels per block (both layers)
constexpr int kHBP   = 12;     // h-buffer row pitch (floats): 48B, 16B-aligned,
                               // bank-stride 12 -> 8 consecutive lanes cover
                               // all 32 banks disjointly for b128 reads
constexpr int kSBP   = 520;    // cur/sbuf row pitch: breaks 512-stride conflicts

__device__ __forceinline__ int decay_i(int x, int mult) {
    unsigned ax = (x >= 0) ? (unsigned)x : (0u - (unsigned)x);
    unsigned p  = ax * (unsigned)mult;   // int32 wrap like jnp
    int sh = ((int)p) >> 12;             // arithmetic shift like jnp int32 >>
    return (x >= 0) ? sh : (int)(0u - (unsigned)sh);
}

// taps kerf[tau] = (64*SRM_KERNEL[tau])/64, exact in f32 (values <= 194)
__device__ __forceinline__ int build_ker_f(float* kerf) {
    int u = 64, v = 64;
    kerf[0] = 1.0f;
    int i = 1;
    while (v > 0 && i < kKMAX) {
        u = (u * 3072) >> 12;
        v = ((v * 3968) >> 12) + u;
        kerf[i++] = (float)v * 0.015625f;
    }
    return i;  // 88, includes trailing zero tap (harmless)
}

// ================= Layer 1: sparse f32 GEMM + conv + int32 scan ==============
__global__ __launch_bounds__(512) void k1_fused(const float* __restrict__ X,
                                                const float* __restrict__ W,
                                                unsigned char* __restrict__ SPT) {
#pragma clang fp contract(off)
    __shared__ float         wlo[kCIN * 4];     // W[o..o+3][i] as [i][4], 8 KB
    __shared__ float         whi[kCIN * 4];     // W[o+4..o+7][i],        8 KB
    __shared__ float         hbf[kT * kHBP];    // 24 KB (aliased as curi later)
    __shared__ unsigned char sbuf[kOT * kSBP];  // 4.1 KB
    __shared__ float         kerf[kKMAX];
    __shared__ int           kn_s;

    const int t     = threadIdx.x;              // one thread per timestep
    const int b     = blockIdx.x >> 7;          // 128 blocks per batch
    const int oblk  = blockIdx.x & 127;
    const int obase = oblk * kOT;

    if (t == 0) kn_s = build_ker_f(kerf);
    for (int idx = t; idx < kOT * kCIN; idx += 512) {
        const int j = idx >> 9, i = idx & 511;
        const float w = W[(size_t)(obase + j) * kCIN + i];
        if (j < 4) wlo[i * 4 + j] = w; else whi[i * 4 + (j - 4)] = w;
    }
    __syncthreads();

    // ---- pack X[:,t] bits + sparse ordered gather (ascending i) ----
    const float* xb = X + ((size_t)b * kCIN) * kT + t;
    float acc[kOT];
#pragma unroll
    for (int j = 0; j < kOT; ++j) acc[j] = 0.0f;
#pragma unroll
    for (int w = 0; w < 16; ++w) {              // 16 x 32 = 512 inputs
        unsigned mw = 0;
        for (int k = 0; k < 32; ++k) {
            const float xv = xb[(size_t)(w * 32 + k) * kT];  // coalesced
            mw |= (xv != 0.0f ? 1u : 0u) << k;
        }
        while (mw) {
            const int bit = __ffs(mw) - 1; mw &= mw - 1;
            const int i = (w << 5) + bit;
            const float4 lo = *reinterpret_cast<const float4*>(&wlo[i * 4]);
            const float4 hi = *reinterpret_cast<const float4*>(&whi[i * 4]);
            acc[0] = acc[0] + lo.x; acc[1] = acc[1] + lo.y;
            acc[2] = acc[2] + lo.z; acc[3] = acc[3] + lo.w;
            acc[4] = acc[4] + hi.x; acc[5] = acc[5] + hi.y;
            acc[6] = acc[6] + hi.z; acc[7] = acc[7] + hi.w;
        }
    }

    // ---- stage h for all 8 channels, then conv (oldest tap first) ----
#pragma unroll
    for (int j = 0; j < kOT; ++j) hbf[t * kHBP + j] = acc[j];
    __syncthreads();

    float c8[kOT];
#pragma unroll
    for (int j = 0; j < kOT; ++j) c8[j] = 0.0f;
    const int kmax = min(t + 1, kn_s);
    for (int tau = kmax - 1; tau >= 0; --tau) {
        const float  kv = kerf[tau];
        const float4 lo = *reinterpret_cast<const float4*>(&hbf[(t - tau) * kHBP]);
        const float4 hi = *reinterpret_cast<const float4*>(&hbf[(t - tau) * kHBP + 4]);
        c8[0] = c8[0] + kv * lo.x; c8[1] = c8[1] + kv * lo.y;
        c8[2] = c8[2] + kv * lo.z; c8[3] = c8[3] + kv * lo.w;
        c8[4] = c8[4] + kv * hi.x; c8[5] = c8[5] + kv * hi.y;
        c8[6] = c8[6] + kv * hi.z; c8[7] = c8[7] + kv * hi.w;
    }
    __syncthreads();                            // all hbf reads done

    int* curi = reinterpret_cast<int*>(hbf);    // alias: 8*520*4 B <= 24 KB
#pragma unroll
    for (int j = 0; j < kOT; ++j)
        curi[j * kSBP + t] = (int)(c8[j] * 64.0f);  // *64 exact, trunc
    __syncthreads();

    // ---- serial int32 Loihi dynamics (8 lanes), PRE-DELAYED spikes ----
    if (t < kOT) {
        int u = 0, v = 0;
        sbuf[t * kSBP + 0] = 0;                 // delay_shift
        const int* cr = &curi[t * kSBP];
        for (int s = 0; s < kT; ++s) {
            const int un = (int)((unsigned)decay_i(u, 3072) + (unsigned)cr[s]);
            int vn = (int)((unsigned)decay_i(v, 3968) + (unsigned)un);
            const int sp = (vn >= kTHETA) ? 1 : 0;
            if (sp) vn = 0;
            u = un; v = vn;
            if (s + 1 < kT) sbuf[t * kSBP + s + 1] = (unsigned char)sp;
        }
    }
    __syncthreads();

    // ---- write byte-column spikes: SPT[b][oblk][t], coalesced over t ----
    unsigned byte = 0;
#pragma unroll
    for (int j = 0; j < kOT; ++j)
        byte |= (unsigned)sbuf[j * kSBP + t] << j;
    SPT[((size_t)b * 128 + oblk) * kT + t] = (unsigned char)byte;
}

// ================= Layer 2: sparse GEMM over spike bytes + conv + scan =======
__global__ __launch_bounds__(512) void k2_fused(const unsigned char* __restrict__ SPT,
                                                const float* __restrict__ W,
                                                float* __restrict__ O) {
#pragma clang fp contract(off)
    __shared__ float         wlo[kHID * 4];     // 16 KB
    __shared__ float         whi[kHID * 4];     // 16 KB
    __shared__ float         hbf[kT * kHBP];    // 24 KB (aliased as curi)
    __shared__ unsigned char sbuf[kOT * kSBP];  // 4.1 KB  => ~61.9 KB total
    __shared__ float         kerf[kKMAX];
    __shared__ int           kn_s;

    const int t     = threadIdx.x;
    const int b     = blockIdx.x >> 5;          // 32 blocks per batch
    const int obase = (blockIdx.x & 31) * kOT;

    if (t == 0) kn_s = build_ker_f(kerf);
    for (int idx = t; idx < kOT * kHID; idx += 512) {
        const int j = idx >> 10, i = idx & 1023;
        const float w = W[(size_t)(obase + j) * kHID + i];
        if (j < 4) wlo[i * 4 + j] = w; else whi[i * 4 + (j - 4)] = w;
    }
    __syncthreads();

    // ---- sparse ordered gather over 1024 packed spike bits (ascending i) ----
    const unsigned char* sp = SPT + ((size_t)b * 128) * kT + t;
    float acc[kOT];
#pragma unroll
    for (int j = 0; j < kOT; ++j) acc[j] = 0.0f;
    for (int cb = 0; cb < 128; cb += 8) {
        unsigned m0, m1, m2, m3, m4, m5, m6, m7;
        m0 = sp[(size_t)(cb + 0) * kT]; m1 = sp[(size_t)(cb + 1) * kT];
        m2 = sp[(size_t)(cb + 2) * kT]; m3 = sp[(size_t)(cb + 3) * kT];
        m4 = sp[(size_t)(cb + 4) * kT]; m5 = sp[(size_t)(cb + 5) * kT];
        m6 = sp[(size_t)(cb + 6) * kT]; m7 = sp[(size_t)(cb + 7) * kT];
        unsigned ms[8] = {m0, m1, m2, m3, m4, m5, m6, m7};
#pragma unroll
        for (int k = 0; k < 8; ++k) {
            unsigned m = ms[k];
            while (m) {
                const int bit = __ffs(m) - 1; m &= m - 1;
                const int i = (cb + k) * 8 + bit;
                const float4 lo = *reinterpret_cast<const float4*>(&wlo[i * 4]);
                const float4 hi = *reinterpret_cast<const float4*>(&whi[i * 4]);
                acc[0] = acc[0] + lo.x; acc[1] = acc[1] + lo.y;
                acc[2] = acc[2] + lo.z; acc[3] = acc[3] + lo.w;
                acc[4] = acc[4] + hi.x; acc[5] = acc[5] + hi.y;
                acc[6] = acc[6] + hi.z; acc[7] = acc[7] + hi.w;
            }
        }
    }

#pragma unroll
    for (int j = 0; j < kOT; ++j) hbf[t * kHBP + j] = acc[j];
    __syncthreads();

    float c8[kOT];
#pragma unroll
    for (int j = 0; j < kOT; ++j) c8[j] = 0.0f;
    const int kmax = min(t + 1, kn_s);
    for (int tau = kmax - 1; tau >= 0; --tau) {
        const float  kv = kerf[tau];
        const float4 lo = *reinterpret_cast<const float4*>(&hbf[(t - tau) * kHBP]);
        const float4 hi = *reinterpret_cast<const float4*>(&hbf[(t - tau) * kHBP + 4]);
        c8[0] = c8[0] + kv * lo.x; c8[1] = c8[1] + kv * lo.y;
        c8[2] = c8[2] + kv * lo.z; c8[3] = c8[3] + kv * lo.w;
        c8[4] = c8[4] + kv * hi.x; c8[5] = c8[5] + kv * hi.y;
        c8[6] = c8[6] + kv * hi.z; c8[7] = c8[7] + kv * hi.w;
    }
    __syncthreads();

    int* curi = reinterpret_cast<int*>(hbf);
#pragma unroll
    for (int j = 0; j < kOT; ++j)
        curi[j * kSBP + t] = (int)(c8[j] * 64.0f);
    __syncthreads();

    if (t < kOT) {
        int u = 0, v = 0;
        sbuf[t * kSBP + 0] = 0;                 // delay_shift on final output
        const int* cr = &curi[t * kSBP];
        for (int s = 0; s < kT; ++s) {
            const int un = (int)((unsigned)decay_i(u, 3072) + (unsigned)cr[s]);
            int vn = (int)((unsigned)decay_i(v, 3968) + (unsigned)un);
            const int sp2 = (vn >= kTHETA) ? 1 : 0;
            if (sp2) vn = 0;
            u = un; v = vn;
            if (s + 1 < kT) sbuf[t * kSBP + s + 1] = (unsigned char)sp2;
        }
    }
    __syncthreads();

    for (int idx = t; idx < kOT * kT; idx += 512) {
        const int j = idx >> 9, tt = idx & 511;
        O[((size_t)(b * kCOUT + obase + j)) * kT + tt] = (float)sbuf[j * kSBP + tt];
    }
}

extern "C" void kernel_launch(void* const* d_in, const int* in_sizes, int n_in,
                              void* d_out, int out_size, void* d_ws, size_t ws_size,
                              hipStream_t stream) {
    const float* X  = (const float*)d_in[0];   // (32,512,1,1,512) spikes {0,1}
    const float* W1 = (const float*)d_in[1];   // (1024,512)
    const float* W2 = (const float*)d_in[2];   // (256,1024)
    float* OUT = (float*)d_out;                // (32,256,1,1,512)

    // byte-column delayed L1 spikes: [b][128 byte-cols][512 t] = 2 MiB
    unsigned char* spt = (unsigned char*)d_ws;

    hipLaunchKernelGGL(k1_fused, dim3(kB * (kHID / kOT)), dim3(512), 0, stream,
                       X, W1, spt);
    hipLaunchKernelGGL(k2_fused, dim3(kB * (kCOUT / kOT)), dim3(512), 0, stream,
                       spt, W2, OUT);
}